// Round 3
// baseline (875.204 us; speedup 1.0000x reference)
//
#include <hip/hip_runtime.h>

#define THRF 0.05f

// ---------------------------------------------------------------------------
// Stage 0: latency encode -> per-pixel spike time tn in [0,19], or -1 if x<thr
// ---------------------------------------------------------------------------
__global__ void k_encode(const float* __restrict__ x, int* __restrict__ tn, int n) {
  int i = blockIdx.x * blockDim.x + threadIdx.x;
  if (i >= n) return;
  float xv = x[i];
  float st = fminf(19.0f * (1.0f - xv), 19.0f * 0.95f);
  int t = (int)rintf(st);
  t = t < 0 ? 0 : (t > 19 ? 19 : t);
  tn[i] = (xv >= THRF) ? t : -1;
}

// ---------------------------------------------------------------------------
// Stage 1: conv1(3x3 SAME, 1->32) + IafPscDelta (T=20) + maxpool 2x2.
// One thread per pooled output (b, oc, py, px) in [128,32,14,14].
// ic=1 so any sequential (ky,kx) order matches the reference conv exactly
// (skipped zero terms are exact no-ops; <=2-term sums are grouping-invariant).
// Output layout: z1p[((b*14+py)*14+px)*32 + oc]  (ic fastest, for stage 2).
// ---------------------------------------------------------------------------
__global__ void k_stage1(const int* __restrict__ tn, const float* __restrict__ W1,
                         unsigned* __restrict__ z1p) {
  int idx = blockIdx.x * blockDim.x + threadIdx.x;
  if (idx >= 128 * 32 * 14 * 14) return;
  int px = idx % 14;
  int py = (idx / 14) % 14;
  int oc = (idx / 196) % 32;
  int b  = idx / (196 * 32);

  float w[9];
  for (int k = 0; k < 9; ++k) w[k] = W1[oc * 9 + k];

  int tr[16];
  const int* tb = tn + b * 784;
  for (int dy = 0; dy < 4; ++dy) {
    int y = 2 * py - 1 + dy;
    for (int dx = 0; dx < 4; ++dx) {
      int xx = 2 * px - 1 + dx;
      tr[dy * 4 + dx] = (y >= 0 && y < 28 && xx >= 0 && xx < 28) ? tb[y * 28 + xx] : -1;
    }
  }

  float v0 = 0.f, v1 = 0.f, v2 = 0.f, v3 = 0.f;
  int   r0 = 0, r1 = 0, r2 = 0, r3 = 0;
  unsigned outm = 0u;
  for (int t = 0; t < 20; ++t) {
    float c0 = 0.f, c1 = 0.f, c2 = 0.f, c3 = 0.f;
    for (int ky = 0; ky < 3; ++ky) {
      for (int kx = 0; kx < 3; ++kx) {
        float wv = w[ky * 3 + kx];
        c0 += (tr[(ky + 0) * 4 + kx + 0] == t) ? wv : 0.0f;
        c1 += (tr[(ky + 0) * 4 + kx + 1] == t) ? wv : 0.0f;
        c2 += (tr[(ky + 1) * 4 + kx + 0] == t) ? wv : 0.0f;
        c3 += (tr[(ky + 1) * 4 + kx + 1] == t) ? wv : 0.0f;
      }
    }
    v0 += c0; v1 += c1; v2 += c2; v3 += c3;
    bool z0 = (v0 > THRF) && (r0 == 0);
    bool z1 = (v1 > THRF) && (r1 == 0);
    bool z2 = (v2 > THRF) && (r2 == 0);
    bool z3 = (v3 > THRF) && (r3 == 0);
    if (z0) { v0 -= THRF; r0 = 3; } else if (r0 > 0) --r0;
    if (z1) { v1 -= THRF; r1 = 3; } else if (r1 > 0) --r1;
    if (z2) { v2 -= THRF; r2 = 3; } else if (r2 > 0) --r2;
    if (z3) { v3 -= THRF; r3 = 3; } else if (r3 > 0) --r3;
    if (z0 || z1 || z2 || z3) outm |= 1u << t;
  }
  z1p[((b * 14 + py) * 14 + px) * 32 + oc] = outm;
}

// ---------------------------------------------------------------------------
// Stage 2: conv2(3x3 SAME, 32->32) + LIF + maxpool 2x2.
// One thread per pooled output (b, oc, py, px) in [128,32,7,7].
// Accumulation order per neuron-step: ascending (ky, kx, ic) with ic
// INNERMOST — Eigen/XLA-CPU's NHWC im2col reduction order. Skipped zero
// terms (OOB cells, empty masks) are exact no-ops.
// ---------------------------------------------------------------------------
__global__ void k_stage2(const unsigned* __restrict__ z1p, const float* __restrict__ W2,
                         unsigned* __restrict__ z2p) {
  int idx = blockIdx.x * blockDim.x + threadIdx.x;
  if (idx >= 128 * 32 * 7 * 7) return;
  int px = idx % 7;
  int py = (idx / 7) % 7;
  int oc = (idx / 49) % 32;
  int b  = idx / (49 * 32);

  const float* w2 = W2 + oc * 288;
  unsigned outm = 0u;

  for (int p = 0; p < 4; ++p) {
    float cur[20];
#pragma unroll
    for (int t = 0; t < 20; ++t) cur[t] = 0.0f;

    int Y = 2 * py + (p >> 1);   // pre-pool row in 14x14
    int X = 2 * px + (p & 1);    // pre-pool col

    for (int ky = 0; ky < 3; ++ky) {
      int y = Y - 1 + ky;
      if (y < 0 || y >= 14) continue;
      for (int kx = 0; kx < 3; ++kx) {
        int xx = X - 1 + kx;
        if (xx < 0 || xx >= 14) continue;
        const unsigned* zc = z1p + ((b * 14 + y) * 14 + xx) * 32;
        const float* wp = w2 + ky * 3 + kx;
        for (int ic = 0; ic < 32; ++ic) {
          unsigned mm = zc[ic];
          if (mm) {
            float wv = wp[ic * 9];
#pragma unroll
            for (int t = 0; t < 20; ++t)
              cur[t] += ((mm >> t) & 1u) ? wv : 0.0f;
          }
        }
      }
    }

    float v = 0.0f;
    int   r = 0;
    unsigned zm = 0u;
#pragma unroll
    for (int t = 0; t < 20; ++t) {
      v += cur[t];
      bool z = (v > THRF) && (r == 0);
      if (z) { v -= THRF; r = 3; } else if (r > 0) --r;
      if (z) zm |= 1u << t;
    }
    outm |= zm;
  }
  z2p[idx] = outm;  // layout [b][f], f = oc*49 + py*7 + px
}

// ---------------------------------------------------------------------------
// Stage 3a: dense currents. One thread per (b, o, t): sequential masked sum
// over f = 0..1567 ascending. t fastest so a wave broadcasts zb[f]/wd[f].
// ---------------------------------------------------------------------------
__global__ void k_dense_cur(const unsigned* __restrict__ z2p, const float* __restrict__ Wd,
                            float* __restrict__ cur) {
  int idx = blockIdx.x * blockDim.x + threadIdx.x;
  if (idx >= 128 * 64 * 20) return;
  int t = idx % 20;
  int o = (idx / 20) % 64;
  int b = idx / (20 * 64);
  const unsigned* zb = z2p + b * 1568;
  const float*    wd = Wd + o * 1568;
  float acc = 0.0f;
  for (int f = 0; f < 1568; ++f) {
    acc += ((zb[f] >> t) & 1u) ? wd[f] : 0.0f;
  }
  cur[idx] = acc;  // layout [b][o][t]
}

// ---------------------------------------------------------------------------
// Stage 3b: output LIF. One thread per (b, o); writes [B, T, 64] f32 spikes.
// ---------------------------------------------------------------------------
__global__ void k_dense_lif(const float* __restrict__ cur, float* __restrict__ out) {
  int idx = blockIdx.x * blockDim.x + threadIdx.x;
  if (idx >= 128 * 64) return;
  int o = idx % 64;
  int b = idx / 64;
  const float* c = cur + (b * 64 + o) * 20;
  float v = 0.0f;
  int   r = 0;
  for (int t = 0; t < 20; ++t) {
    v += c[t];
    bool z = (v > THRF) && (r == 0);
    if (z) { v -= THRF; r = 3; } else if (r > 0) --r;
    out[(b * 20 + t) * 64 + o] = z ? 1.0f : 0.0f;
  }
}

extern "C" void kernel_launch(void* const* d_in, const int* in_sizes, int n_in,
                              void* d_out, int out_size, void* d_ws, size_t ws_size,
                              hipStream_t stream) {
  const float* x  = (const float*)d_in[0];  // [128,1,28,28]
  const float* W1 = (const float*)d_in[1];  // [32,1,3,3]
  const float* W2 = (const float*)d_in[2];  // [32,32,3,3]
  const float* Wd = (const float*)d_in[3];  // [64,1568]
  float* out = (float*)d_out;               // [128,20,64]

  char* ws = (char*)d_ws;
  int*      tn  = (int*)ws;                                   // 128*784*4      = 401408 B
  unsigned* z1p = (unsigned*)(ws + 401408);                   // 128*196*32*4   = 3211264 B
  unsigned* z2p = (unsigned*)(ws + 401408 + 3211264);         // 128*32*49*4    = 802816 B
  float*    cur = (float*)(ws + 401408 + 3211264 + 802816);   // 128*64*20*4    = 655360 B

  k_encode<<<dim3(392), dim3(256), 0, stream>>>(x, tn, 128 * 784);
  k_stage1<<<dim3(3136), dim3(256), 0, stream>>>(tn, W1, z1p);
  k_stage2<<<dim3(784), dim3(256), 0, stream>>>(z1p, W2, z2p);
  k_dense_cur<<<dim3(640), dim3(256), 0, stream>>>(z2p, Wd, cur);
  k_dense_lif<<<dim3(32), dim3(256), 0, stream>>>(cur, out);
}

// Round 4
// 493.073 us; speedup vs baseline: 1.7750x; 1.7750x over previous
//
#include <hip/hip_runtime.h>

#define THRF 0.05f

// ---------------------------------------------------------------------------
// Stage 0: latency encode -> per-pixel spike time tn in [0,19], or -1 if x<thr
// ---------------------------------------------------------------------------
__global__ void k_encode(const float* __restrict__ x, int* __restrict__ tn, int n) {
  int i = blockIdx.x * blockDim.x + threadIdx.x;
  if (i >= n) return;
  float xv = x[i];
  float st = fminf(19.0f * (1.0f - xv), 19.0f * 0.95f);
  int t = (int)rintf(st);
  t = t < 0 ? 0 : (t > 19 ? 19 : t);
  tn[i] = (xv >= THRF) ? t : -1;
}

// ---------------------------------------------------------------------------
// Stage 1: conv1(3x3 SAME, 1->32) + IafPscDelta (T=20) + maxpool 2x2.
// (unchanged from passing round-3 kernel)
// Output layout: z1p[((b*14+py)*14+px)*32 + oc]  (ic fastest, for stage 2).
// ---------------------------------------------------------------------------
__global__ void k_stage1(const int* __restrict__ tn, const float* __restrict__ W1,
                         unsigned* __restrict__ z1p) {
  int idx = blockIdx.x * blockDim.x + threadIdx.x;
  if (idx >= 128 * 32 * 14 * 14) return;
  int px = idx % 14;
  int py = (idx / 14) % 14;
  int oc = (idx / 196) % 32;
  int b  = idx / (196 * 32);

  float w[9];
  for (int k = 0; k < 9; ++k) w[k] = W1[oc * 9 + k];

  int tr[16];
  const int* tb = tn + b * 784;
  for (int dy = 0; dy < 4; ++dy) {
    int y = 2 * py - 1 + dy;
    for (int dx = 0; dx < 4; ++dx) {
      int xx = 2 * px - 1 + dx;
      tr[dy * 4 + dx] = (y >= 0 && y < 28 && xx >= 0 && xx < 28) ? tb[y * 28 + xx] : -1;
    }
  }

  float v0 = 0.f, v1 = 0.f, v2 = 0.f, v3 = 0.f;
  int   r0 = 0, r1 = 0, r2 = 0, r3 = 0;
  unsigned outm = 0u;
  for (int t = 0; t < 20; ++t) {
    float c0 = 0.f, c1 = 0.f, c2 = 0.f, c3 = 0.f;
    for (int ky = 0; ky < 3; ++ky) {
      for (int kx = 0; kx < 3; ++kx) {
        float wv = w[ky * 3 + kx];
        c0 += (tr[(ky + 0) * 4 + kx + 0] == t) ? wv : 0.0f;
        c1 += (tr[(ky + 0) * 4 + kx + 1] == t) ? wv : 0.0f;
        c2 += (tr[(ky + 1) * 4 + kx + 0] == t) ? wv : 0.0f;
        c3 += (tr[(ky + 1) * 4 + kx + 1] == t) ? wv : 0.0f;
      }
    }
    v0 += c0; v1 += c1; v2 += c2; v3 += c3;
    bool z0 = (v0 > THRF) && (r0 == 0);
    bool z1 = (v1 > THRF) && (r1 == 0);
    bool z2 = (v2 > THRF) && (r2 == 0);
    bool z3 = (v3 > THRF) && (r3 == 0);
    if (z0) { v0 -= THRF; r0 = 3; } else if (r0 > 0) --r0;
    if (z1) { v1 -= THRF; r1 = 3; } else if (r1 > 0) --r1;
    if (z2) { v2 -= THRF; r2 = 3; } else if (r2 > 0) --r2;
    if (z3) { v3 -= THRF; r3 = 3; } else if (r3 > 0) --r3;
    if (z0 || z1 || z2 || z3) outm |= 1u << t;
  }
  z1p[((b * 14 + py) * 14 + px) * 32 + oc] = outm;
}

// ---------------------------------------------------------------------------
// W2 transpose: wT[(ic*9+ky*3+kx)*32 + oc] = W2[oc*288 + ic*9+ky*3+kx]
// so the 32 oc-weights for a given (ky,kx,ic) are contiguous (-> s_load x16).
// ---------------------------------------------------------------------------
__global__ void k_w2t(const float* __restrict__ W2, float* __restrict__ wT) {
  int i = blockIdx.x * blockDim.x + threadIdx.x;
  if (i >= 9216) return;
  int oc = i / 288, k = i % 288;
  wT[k * 32 + oc] = W2[i];
}

// ---------------------------------------------------------------------------
// Stage 2 rewrite: one wave = 2 pre-pool pixels, lanes = (pixel-half, t).
// Per (ky,kx,ic): masks are wave-uniform (scalar loads), bit extracted once
// per lane; each oc costs ONE v_fmac with an SGPR weight. Accumulation order
// per (neuron,t): ascending (ky,kx,ic) with ic innermost — identical to the
// passing round-3 kernel; fmaf(w, bit∈{0,1}, acc) rounds identically to the
// reference's add (product exact; w*0 adds ±0 = exact no-op).
// Epilogue: LDS transpose (stride 65, conflict-free) -> lanes = (pixel, oc),
// LIF over t in-register, 2x2 max-pool via deterministic atomicOr.
// ---------------------------------------------------------------------------
__global__ __launch_bounds__(256) void k_stage2A(const unsigned* __restrict__ z1p,
                                                 const float* __restrict__ wT,
                                                 unsigned* __restrict__ z2p) {
  __shared__ float xp[4][32 * 65];
  int lane = threadIdx.x & 63;
  int wid  = __builtin_amdgcn_readfirstlane(threadIdx.x >> 6);
  int gw   = blockIdx.x * 4 + wid;           // pixel-pair index, uniform
  int pA = 2 * gw, pB = 2 * gw + 1;          // linear pixel = b*196 + y*14 + x
  int bA = pA / 196, rA = pA % 196, yA = rA / 14, xA = rA % 14;
  int bB = pB / 196, rB = pB % 196, yB = rB / 14, xB = rB % 14;
  int  tl  = lane & 31;
  bool hiB = (lane & 32) != 0;

  float acc[32];
#pragma unroll
  for (int o = 0; o < 32; ++o) acc[o] = 0.0f;

  for (int ky = 0; ky < 3; ++ky) {
    int yAk = yA - 1 + ky, yBk = yB - 1 + ky;
    for (int kx = 0; kx < 3; ++kx) {
      int xAk = xA - 1 + kx, xBk = xB - 1 + kx;
      bool okA = (yAk >= 0 && yAk < 14 && xAk >= 0 && xAk < 14);
      bool okB = (yBk >= 0 && yBk < 14 && xBk >= 0 && xBk < 14);
      const unsigned* mAp = z1p + ((bA * 14 + yAk) * 14 + xAk) * 32;
      const unsigned* mBp = z1p + ((bB * 14 + yBk) * 14 + xBk) * 32;
      const float* wk = wT + (ky * 3 + kx) * 32;
      for (int ic = 0; ic < 32; ++ic) {
        unsigned mmA = okA ? mAp[ic] : 0u;   // wave-uniform
        unsigned mmB = okB ? mBp[ic] : 0u;   // wave-uniform
        if ((mmA | mmB) == 0u) continue;     // uniform branch; exact no-op skip
        unsigned mm = hiB ? mmB : mmA;
        float bitf = (float)((mm >> tl) & 1u);   // lanes tl>=20 -> always 0
        const float* wrow = wk + ic * 288;
#pragma unroll
        for (int oc = 0; oc < 32; ++oc)
          acc[oc] = fmaf(wrow[oc], bitf, acc[oc]);
      }
    }
  }

  // transpose: [oc][half*32+t] so each lane can read one neuron's time series
  int base_w = (hiB ? 32 : 0) + tl;
#pragma unroll
  for (int oc = 0; oc < 32; ++oc)
    xp[wid][oc * 65 + base_w] = acc[oc];
  __syncthreads();

  int half2 = lane >> 5;   // which pixel
  int ocr   = lane & 31;   // which channel
  float v = 0.0f;
  int   r = 0;
  unsigned zm = 0u;
#pragma unroll
  for (int t = 0; t < 20; ++t) {
    float c = xp[wid][ocr * 65 + half2 * 32 + t];
    v += c;
    bool z = (v > THRF) && (r == 0);
    if (z) { v -= THRF; r = 3; } else if (r > 0) --r;
    if (z) zm |= 1u << t;
  }
  int p = half2 ? pB : pA;
  int b = p / 196, rr = p % 196, y = rr / 14, x = rr % 14;
  // 2x2 max-pool of binary spikes == OR; atomicOr is order-independent.
  atomicOr(&z2p[b * 1568 + ocr * 49 + (y >> 1) * 7 + (x >> 1)], zm);
}

// ---------------------------------------------------------------------------
// Stage 3a: dense currents (unchanged). One thread per (b,o,t).
// ---------------------------------------------------------------------------
__global__ void k_dense_cur(const unsigned* __restrict__ z2p, const float* __restrict__ Wd,
                            float* __restrict__ cur) {
  int idx = blockIdx.x * blockDim.x + threadIdx.x;
  if (idx >= 128 * 64 * 20) return;
  int t = idx % 20;
  int o = (idx / 20) % 64;
  int b = idx / (20 * 64);
  const unsigned* zb = z2p + b * 1568;
  const float*    wd = Wd + o * 1568;
  float acc = 0.0f;
  for (int f = 0; f < 1568; ++f) {
    acc += ((zb[f] >> t) & 1u) ? wd[f] : 0.0f;
  }
  cur[idx] = acc;
}

// ---------------------------------------------------------------------------
// Stage 3b: output LIF (unchanged). One thread per (b,o) -> [B,T,64] f32.
// ---------------------------------------------------------------------------
__global__ void k_dense_lif(const float* __restrict__ cur, float* __restrict__ out) {
  int idx = blockIdx.x * blockDim.x + threadIdx.x;
  if (idx >= 128 * 64) return;
  int o = idx % 64;
  int b = idx / 64;
  const float* c = cur + (b * 64 + o) * 20;
  float v = 0.0f;
  int   r = 0;
  for (int t = 0; t < 20; ++t) {
    v += c[t];
    bool z = (v > THRF) && (r == 0);
    if (z) { v -= THRF; r = 3; } else if (r > 0) --r;
    out[(b * 20 + t) * 64 + o] = z ? 1.0f : 0.0f;
  }
}

extern "C" void kernel_launch(void* const* d_in, const int* in_sizes, int n_in,
                              void* d_out, int out_size, void* d_ws, size_t ws_size,
                              hipStream_t stream) {
  const float* x  = (const float*)d_in[0];  // [128,1,28,28]
  const float* W1 = (const float*)d_in[1];  // [32,1,3,3]
  const float* W2 = (const float*)d_in[2];  // [32,32,3,3]
  const float* Wd = (const float*)d_in[3];  // [64,1568]
  float* out = (float*)d_out;               // [128,20,64]

  char* ws = (char*)d_ws;
  int*      tn  = (int*)ws;                                   // 0 .. 401408 (dead after stage1)
  float*    wT  = (float*)ws;                                 // reuses tn region (36864 B)
  unsigned* z1p = (unsigned*)(ws + 401408);                   // 3211264 B
  unsigned* z2p = (unsigned*)(ws + 401408 + 3211264);         // 802816 B
  float*    cur = (float*)(ws + 401408 + 3211264 + 802816);   // 655360 B

  k_encode<<<dim3(392), dim3(256), 0, stream>>>(x, tn, 128 * 784);
  k_stage1<<<dim3(3136), dim3(256), 0, stream>>>(tn, W1, z1p);
  k_w2t<<<dim3(36), dim3(256), 0, stream>>>(W2, wT);          // after stage1: tn dead
  hipMemsetAsync(z2p, 0, 802816, stream);                     // zero for atomicOr pooling
  k_stage2A<<<dim3(3136), dim3(256), 0, stream>>>(z1p, wT, z2p);
  k_dense_cur<<<dim3(640), dim3(256), 0, stream>>>(z2p, Wd, cur);
  k_dense_lif<<<dim3(32), dim3(256), 0, stream>>>(cur, out);
}

// Round 5
// 407.074 us; speedup vs baseline: 2.1500x; 1.2113x over previous
//
#include <hip/hip_runtime.h>

#define THRF 0.05f

// ---------------------------------------------------------------------------
// Stage 0: latency encode -> per-pixel spike time tn in [0,19], or -1 if x<thr
// ---------------------------------------------------------------------------
__global__ void k_encode(const float* __restrict__ x, int* __restrict__ tn, int n) {
  int i = blockIdx.x * blockDim.x + threadIdx.x;
  if (i >= n) return;
  float xv = x[i];
  float st = fminf(19.0f * (1.0f - xv), 19.0f * 0.95f);
  int t = (int)rintf(st);
  t = t < 0 ? 0 : (t > 19 ? 19 : t);
  tn[i] = (xv >= THRF) ? t : -1;
}

// ---------------------------------------------------------------------------
// Stage 1: conv1(3x3 SAME, 1->32) + IafPscDelta (T=20) + maxpool 2x2.
// (unchanged from passing kernel)
// Output layout: z1p[((b*14+py)*14+px)*32 + oc]  (ic fastest, for stage 2).
// ---------------------------------------------------------------------------
__global__ void k_stage1(const int* __restrict__ tn, const float* __restrict__ W1,
                         unsigned* __restrict__ z1p) {
  int idx = blockIdx.x * blockDim.x + threadIdx.x;
  if (idx >= 128 * 32 * 14 * 14) return;
  int px = idx % 14;
  int py = (idx / 14) % 14;
  int oc = (idx / 196) % 32;
  int b  = idx / (196 * 32);

  float w[9];
  for (int k = 0; k < 9; ++k) w[k] = W1[oc * 9 + k];

  int tr[16];
  const int* tb = tn + b * 784;
  for (int dy = 0; dy < 4; ++dy) {
    int y = 2 * py - 1 + dy;
    for (int dx = 0; dx < 4; ++dx) {
      int xx = 2 * px - 1 + dx;
      tr[dy * 4 + dx] = (y >= 0 && y < 28 && xx >= 0 && xx < 28) ? tb[y * 28 + xx] : -1;
    }
  }

  float v0 = 0.f, v1 = 0.f, v2 = 0.f, v3 = 0.f;
  int   r0 = 0, r1 = 0, r2 = 0, r3 = 0;
  unsigned outm = 0u;
  for (int t = 0; t < 20; ++t) {
    float c0 = 0.f, c1 = 0.f, c2 = 0.f, c3 = 0.f;
    for (int ky = 0; ky < 3; ++ky) {
      for (int kx = 0; kx < 3; ++kx) {
        float wv = w[ky * 3 + kx];
        c0 += (tr[(ky + 0) * 4 + kx + 0] == t) ? wv : 0.0f;
        c1 += (tr[(ky + 0) * 4 + kx + 1] == t) ? wv : 0.0f;
        c2 += (tr[(ky + 1) * 4 + kx + 0] == t) ? wv : 0.0f;
        c3 += (tr[(ky + 1) * 4 + kx + 1] == t) ? wv : 0.0f;
      }
    }
    v0 += c0; v1 += c1; v2 += c2; v3 += c3;
    bool z0 = (v0 > THRF) && (r0 == 0);
    bool z1 = (v1 > THRF) && (r1 == 0);
    bool z2 = (v2 > THRF) && (r2 == 0);
    bool z3 = (v3 > THRF) && (r3 == 0);
    if (z0) { v0 -= THRF; r0 = 3; } else if (r0 > 0) --r0;
    if (z1) { v1 -= THRF; r1 = 3; } else if (r1 > 0) --r1;
    if (z2) { v2 -= THRF; r2 = 3; } else if (r2 > 0) --r2;
    if (z3) { v3 -= THRF; r3 = 3; } else if (r3 > 0) --r3;
    if (z0 || z1 || z2 || z3) outm |= 1u << t;
  }
  z1p[((b * 14 + py) * 14 + px) * 32 + oc] = outm;
}

// ---------------------------------------------------------------------------
// W2 repack: wT2[(ky*3+kx)*1024 + ic*32 + oc] = W2[oc*288 + ic*9 + ky*3 + kx]
// Per (ky,kx) cell: 4 KB of weights contiguous, ic-major -> the inner loop's
// s_loads are immediate-offset and merge into dwordx16 streams.
// ---------------------------------------------------------------------------
__global__ void k_w2t(const float* __restrict__ W2, float* __restrict__ wT2) {
  int i = blockIdx.x * blockDim.x + threadIdx.x;
  if (i >= 9216) return;
  int oc = i / 288, k = i % 288;
  int ic = k / 9, kk = k % 9;
  wT2[kk * 1024 + ic * 32 + oc] = W2[i];
}

// ---------------------------------------------------------------------------
// Stage 2: one wave = 2 pre-pool pixels; lanes = (pixel-half, t-slot).
// Branchless: OOB cells read a 128-B zero buffer, so every (ky,kx,ic) term
// is an unconditional fmaf(w, bit, acc) — bit=0 adds ±0, an exact no-op,
// exactly as the reference's dense conv does. Accumulation order per
// (neuron,t): ascending (ky,kx,ic), ic innermost — identical to the passing
// kernel. Masks for a cell (128 B) and weights (4 KB, contiguous) are
// wave-uniform scalar loads, mergeable and prefetchable.
// Epilogue: LDS transpose [t][neuron] (stride 66, conflict-free), LIF over t
// in-register, 2x2 max-pool via deterministic atomicOr into pre-zeroed z2p.
// ---------------------------------------------------------------------------
__global__ __launch_bounds__(256) void k_stage2B(const unsigned* __restrict__ z1p,
                                                 const float* __restrict__ wT2,
                                                 const unsigned* __restrict__ zbuf,
                                                 unsigned* __restrict__ z2p) {
  __shared__ float xp[4][20 * 66];
  int lane = threadIdx.x & 63;
  int wid  = threadIdx.x >> 6;
  int gw   = blockIdx.x * 4 + wid;           // pixel-pair index (wave-uniform)
  int pA = 2 * gw, pB = 2 * gw + 1;          // linear pixel = b*196 + y*14 + x
  int bA = pA / 196, rA = pA % 196, yA = rA / 14, xA = rA % 14;
  int bB = pB / 196, rB = pB % 196, yB = rB / 14, xB = rB % 14;

  float acc[32];
#pragma unroll
  for (int o = 0; o < 32; ++o) acc[o] = 0.0f;

  for (int ky = 0; ky < 3; ++ky) {
    int yAk = yA - 1 + ky, yBk = yB - 1 + ky;
    for (int kx = 0; kx < 3; ++kx) {
      int xAk = xA - 1 + kx, xBk = xB - 1 + kx;
      bool okA = (yAk >= 0 && yAk < 14 && xAk >= 0 && xAk < 14);
      bool okB = (yBk >= 0 && yBk < 14 && xBk >= 0 && xBk < 14);
      const unsigned* cA = okA ? (z1p + ((bA * 14 + yAk) * 14 + xAk) * 32) : zbuf;
      const unsigned* cB = okB ? (z1p + ((bB * 14 + yBk) * 14 + xBk) * 32) : zbuf;
      const float* wc = wT2 + (ky * 3 + kx) * 1024;
#pragma unroll
      for (int ic = 0; ic < 32; ++ic) {
        unsigned long long m64 =
            ((unsigned long long)cB[ic] << 32) | (unsigned long long)cA[ic];
        float bitf = (float)((m64 >> lane) & 1ull);  // lane = hiB*32 + t-slot
        const float* wrow = wc + ic * 32;
#pragma unroll
        for (int oc = 0; oc < 32; ++oc)
          acc[oc] = fmaf(wrow[oc], bitf, acc[oc]);
      }
    }
  }

  // transpose to [t][neuron], neuron = hiB*32 + oc; stride 66 -> 2-way max
  int tl  = lane & 31;
  int hiB = lane >> 5;
  if (tl < 20) {
#pragma unroll
    for (int oc = 0; oc < 32; ++oc)
      xp[wid][tl * 66 + hiB * 32 + oc] = acc[oc];
  }
  __syncthreads();

  // lane = neuron: pixel = lane>>5, channel = lane&31
  float v = 0.0f;
  int   r = 0;
  unsigned zm = 0u;
#pragma unroll
  for (int t = 0; t < 20; ++t) {
    float c = xp[wid][t * 66 + lane];
    v += c;
    bool z = (v > THRF) && (r == 0);
    if (z) { v -= THRF; r = 3; } else if (r > 0) --r;
    if (z) zm |= 1u << t;
  }
  int p = hiB ? pB : pA;
  int b = p / 196, rr = p % 196, y = rr / 14, x = rr % 14;
  atomicOr(&z2p[b * 1568 + tl * 49 + (y >> 1) * 7 + (x >> 1)], zm);
}

// ---------------------------------------------------------------------------
// Stage 3a: dense currents (unchanged). One thread per (b,o,t).
// ---------------------------------------------------------------------------
__global__ void k_dense_cur(const unsigned* __restrict__ z2p, const float* __restrict__ Wd,
                            float* __restrict__ cur) {
  int idx = blockIdx.x * blockDim.x + threadIdx.x;
  if (idx >= 128 * 64 * 20) return;
  int t = idx % 20;
  int o = (idx / 20) % 64;
  int b = idx / (20 * 64);
  const unsigned* zb = z2p + b * 1568;
  const float*    wd = Wd + o * 1568;
  float acc = 0.0f;
  for (int f = 0; f < 1568; ++f) {
    acc += ((zb[f] >> t) & 1u) ? wd[f] : 0.0f;
  }
  cur[idx] = acc;
}

// ---------------------------------------------------------------------------
// Stage 3b: output LIF (unchanged). One thread per (b,o) -> [B,T,64] f32.
// ---------------------------------------------------------------------------
__global__ void k_dense_lif(const float* __restrict__ cur, float* __restrict__ out) {
  int idx = blockIdx.x * blockDim.x + threadIdx.x;
  if (idx >= 128 * 64) return;
  int o = idx % 64;
  int b = idx / 64;
  const float* c = cur + (b * 64 + o) * 20;
  float v = 0.0f;
  int   r = 0;
  for (int t = 0; t < 20; ++t) {
    v += c[t];
    bool z = (v > THRF) && (r == 0);
    if (z) { v -= THRF; r = 3; } else if (r > 0) --r;
    out[(b * 20 + t) * 64 + o] = z ? 1.0f : 0.0f;
  }
}

extern "C" void kernel_launch(void* const* d_in, const int* in_sizes, int n_in,
                              void* d_out, int out_size, void* d_ws, size_t ws_size,
                              hipStream_t stream) {
  const float* x  = (const float*)d_in[0];  // [128,1,28,28]
  const float* W1 = (const float*)d_in[1];  // [32,1,3,3]
  const float* W2 = (const float*)d_in[2];  // [32,32,3,3]
  const float* Wd = (const float*)d_in[3];  // [64,1568]
  float* out = (float*)d_out;               // [128,20,64]

  char* ws = (char*)d_ws;
  int*      tn  = (int*)ws;                                   // dead after stage1
  float*    wT2 = (float*)ws;                                 // reuses tn region (36864 B)
  unsigned* z1p = (unsigned*)(ws + 401408);                   // 3211264 B
  unsigned* z2p = (unsigned*)(ws + 401408 + 3211264);         // 802816 B
  unsigned* zbuf = (unsigned*)(ws + 401408 + 3211264 + 802816);        // 128 B zeros
  float*    cur = (float*)(ws + 401408 + 3211264 + 802816 + 128);      // 655360 B

  k_encode<<<dim3(392), dim3(256), 0, stream>>>(x, tn, 128 * 784);
  k_stage1<<<dim3(3136), dim3(256), 0, stream>>>(tn, W1, z1p);
  k_w2t<<<dim3(36), dim3(256), 0, stream>>>(W2, wT2);         // after stage1: tn dead
  hipMemsetAsync(z2p, 0, 802816 + 128, stream);               // zero z2p (atomicOr) + zbuf
  k_stage2B<<<dim3(3136), dim3(256), 0, stream>>>(z1p, wT2, zbuf, z2p);
  k_dense_cur<<<dim3(640), dim3(256), 0, stream>>>(z2p, Wd, cur);
  k_dense_lif<<<dim3(32), dim3(256), 0, stream>>>(cur, out);
}

// Round 6
// 393.692 us; speedup vs baseline: 2.2231x; 1.0340x over previous
//
#include <hip/hip_runtime.h>

#define THRF 0.05f

// ---------------------------------------------------------------------------
// Stage 0: latency encode -> one-hot spike mask per pixel (bit t set, or 0)
// st = min(19*(1-x), 19*0.95); t = clip(rint(st),0,19); no spike if x < thr
// ---------------------------------------------------------------------------
__global__ void k_encode_mask(const float* __restrict__ x, unsigned* __restrict__ m, int n) {
  int i = blockIdx.x * blockDim.x + threadIdx.x;
  if (i >= n) return;
  float xv = x[i];
  float st = fminf(19.0f * (1.0f - xv), 19.0f * 0.95f);
  int t = (int)rintf(st);
  t = t < 0 ? 0 : (t > 19 ? 19 : t);
  m[i] = (xv >= THRF) ? (1u << t) : 0u;
}

// ---------------------------------------------------------------------------
// Weight transposes:
//  w1T[k*32+oc]              = W1[oc*9+k]
//  w2T[kk*1024+ic*32+oc]     = W2[oc*288+ic*9+kk]
//  WdT[f*64+o]               = Wd[o*1568+f]
// ---------------------------------------------------------------------------
__global__ void k_wt(const float* __restrict__ W1, const float* __restrict__ W2,
                     const float* __restrict__ Wd, float* __restrict__ w1T,
                     float* __restrict__ w2T, float* __restrict__ WdT) {
  int i = blockIdx.x * blockDim.x + threadIdx.x;
  if (i < 288) { int oc = i / 9, k = i % 9; w1T[k * 32 + oc] = W1[i]; }
  if (i < 9216) {
    int oc = i / 288, k = i % 288, ic = k / 9, kk = k % 9;
    w2T[kk * 1024 + ic * 32 + oc] = W2[i];
  }
  if (i < 100352) { int o = i / 1568, f = i % 1568; WdT[f * 64 + o] = Wd[i]; }
}

// ---------------------------------------------------------------------------
// Stage 1: conv1(3x3 SAME, 1->32) + LIF + maxpool, lane-parallel over t.
// One wave = 2 pre-pool pixels (28x28 grid); lanes = (pixel-half, t-slot).
// Per k (9, ascending ky,kx = reference order): the two pixels' neighbor
// one-hot masks are packed into a 64-bit scalar; bit extract is 3 VALU;
// 32 fmacs (SGPR weights) serve 2 pixels x 32 t-slots.
// fmaf(w, bit in {0,1}, acc) rounds identically to the reference's add.
// Epilogue: LDS transpose [t][neuron] (stride 66), LIF in-register,
// 2x2 max-pool via deterministic atomicOr into pre-zeroed z1p.
// z1p layout: [((b*14+py)*14+px)*32 + oc]  (ic fastest, for stage 2).
// ---------------------------------------------------------------------------
__global__ __launch_bounds__(128) void k_stage1M(const unsigned* __restrict__ mIn,
                                                 const float* __restrict__ w1T,
                                                 unsigned* __restrict__ z1p) {
  __shared__ float xp[2][20 * 66];
  int lane = threadIdx.x & 63;
  int wid  = threadIdx.x >> 6;
  int gw   = blockIdx.x * 2 + wid;     // wave index (uniform)
  int pA = 2 * gw, pB = 2 * gw + 1;    // pre-pool pixel = b*784 + y*28 + x
  int bA = pA / 784, rA = pA % 784, yA = rA / 28, xA = rA % 28;
  int bB = pB / 784, rB = pB % 784, yB = rB / 28, xB = rB % 28;
  int tl = lane & 31, hiB = lane >> 5;

  unsigned mA[9], mB[9];
  for (int ky = 0; ky < 3; ++ky) {
    for (int kx = 0; kx < 3; ++kx) {
      int k = ky * 3 + kx;
      int ya = yA - 1 + ky, xa = xA - 1 + kx;
      int yb = yB - 1 + ky, xb = xB - 1 + kx;
      mA[k] = (ya >= 0 && ya < 28 && xa >= 0 && xa < 28) ? mIn[bA * 784 + ya * 28 + xa] : 0u;
      mB[k] = (yb >= 0 && yb < 28 && xb >= 0 && xb < 28) ? mIn[bB * 784 + yb * 28 + xb] : 0u;
    }
  }

  float acc[32];
#pragma unroll
  for (int o = 0; o < 32; ++o) acc[o] = 0.0f;

  for (int k = 0; k < 9; ++k) {
    unsigned long long m64 = ((unsigned long long)mB[k] << 32) | (unsigned long long)mA[k];
    float bitf = (float)((m64 >> lane) & 1ull);
    const float* wrow = w1T + k * 32;
#pragma unroll
    for (int oc = 0; oc < 32; ++oc)
      acc[oc] = fmaf(wrow[oc], bitf, acc[oc]);
  }

  if (tl < 20) {
#pragma unroll
    for (int oc = 0; oc < 32; ++oc)
      xp[wid][tl * 66 + hiB * 32 + oc] = acc[oc];
  }
  __syncthreads();

  // lane = neuron: pixel = lane>>5, channel = lane&31
  float v = 0.0f;
  int   r = 0;
  unsigned zm = 0u;
#pragma unroll
  for (int t = 0; t < 20; ++t) {
    float c = xp[wid][t * 66 + lane];
    v += c;
    bool z = (v > THRF) && (r == 0);
    if (z) { v -= THRF; r = 3; } else if (r > 0) --r;
    if (z) zm |= 1u << t;
  }
  int p = hiB ? pB : pA;
  int b = p / 784, rr = p % 784, y = rr / 28, x = rr % 28;
  atomicOr(&z1p[((b * 14 + (y >> 1)) * 14 + (x >> 1)) * 32 + tl], zm);
}

// ---------------------------------------------------------------------------
// Stage 2: conv2(3x3 SAME, 32->32) + LIF + maxpool, 3 pixels per wave.
// lanes = p*20 + t (p=0..2; lanes 60-63 idle). Per (ky,kx,ic) — ascending,
// ic innermost (reference order): the 3 pixels' 20-bit masks pack into one
// 64-bit scalar B = mA | mB<<20 | mC<<40 (SALU); bit extract = shr64+and+cvt
// (3 VALU); 32 fmacs serve 3 pixels. OOB / pad-pixel cells read a zero
// buffer (exact no-op adds). Epilogue: LDS transpose [t][96] stride 97,
// LIF (2 passes over 96 neurons), atomicOr pool into pre-zeroed z2p.
// ---------------------------------------------------------------------------
__global__ __launch_bounds__(128) void k_stage2C(const unsigned* __restrict__ z1p,
                                                 const float* __restrict__ wT2,
                                                 const unsigned* __restrict__ zbuf,
                                                 unsigned* __restrict__ z2p) {
  __shared__ float xp[2][20 * 97];
  int lane = threadIdx.x & 63;
  int wid  = threadIdx.x >> 6;
  int gw   = blockIdx.x * 2 + wid;       // wave index (uniform)
  int q0 = 3 * gw, q1 = q0 + 1, q2 = q0 + 2;   // pixels: b*196 + y*14 + x
  bool v0 = q0 < 25088, v1 = q1 < 25088, v2 = q2 < 25088;
  int b0 = q0 / 196, r0 = q0 % 196, y0 = r0 / 14, x0 = r0 % 14;
  int b1 = q1 / 196, r1 = q1 % 196, y1 = r1 / 14, x1 = r1 % 14;
  int b2 = q2 / 196, r2 = q2 % 196, y2 = r2 / 14, x2 = r2 % 14;

  float acc[32];
#pragma unroll
  for (int o = 0; o < 32; ++o) acc[o] = 0.0f;

  for (int ky = 0; ky < 3; ++ky) {
    int y0k = y0 - 1 + ky, y1k = y1 - 1 + ky, y2k = y2 - 1 + ky;
    for (int kx = 0; kx < 3; ++kx) {
      int x0k = x0 - 1 + kx, x1k = x1 - 1 + kx, x2k = x2 - 1 + kx;
      bool ok0 = v0 && y0k >= 0 && y0k < 14 && x0k >= 0 && x0k < 14;
      bool ok1 = v1 && y1k >= 0 && y1k < 14 && x1k >= 0 && x1k < 14;
      bool ok2 = v2 && y2k >= 0 && y2k < 14 && x2k >= 0 && x2k < 14;
      const unsigned* c0 = ok0 ? (z1p + ((b0 * 14 + y0k) * 14 + x0k) * 32) : zbuf;
      const unsigned* c1 = ok1 ? (z1p + ((b1 * 14 + y1k) * 14 + x1k) * 32) : zbuf;
      const unsigned* c2 = ok2 ? (z1p + ((b2 * 14 + y2k) * 14 + x2k) * 32) : zbuf;
      const float* wc = wT2 + (ky * 3 + kx) * 1024;
#pragma unroll
      for (int ic = 0; ic < 32; ++ic) {
        unsigned long long B = (unsigned long long)c0[ic] |
                               ((unsigned long long)c1[ic] << 20) |
                               ((unsigned long long)c2[ic] << 40);
        float bitf = (float)((B >> lane) & 1ull);   // lane = p*20 + t
        const float* wrow = wc + ic * 32;
#pragma unroll
        for (int oc = 0; oc < 32; ++oc)
          acc[oc] = fmaf(wrow[oc], bitf, acc[oc]);
      }
    }
  }

  // transpose to [t][n], n = p*32 + oc
  int pl = lane / 20;
  int tl = lane - pl * 20;
  if (pl < 3) {
#pragma unroll
    for (int oc = 0; oc < 32; ++oc)
      xp[wid][tl * 97 + pl * 32 + oc] = acc[oc];
  }
  __syncthreads();

  for (int pass = 0; pass < 2; ++pass) {
    int n = lane + 64 * pass;
    if (n < 96) {
      int pp = n >> 5;                 // which pixel of the triple
      int oc = n & 31;
      int q  = q0 + pp;
      if (q < 25088) {
        float v = 0.0f;
        int   r = 0;
        unsigned zm = 0u;
#pragma unroll
        for (int t = 0; t < 20; ++t) {
          float c = xp[wid][t * 97 + n];
          v += c;
          bool z = (v > THRF) && (r == 0);
          if (z) { v -= THRF; r = 3; } else if (r > 0) --r;
          if (z) zm |= 1u << t;
        }
        int b = q / 196, rr = q % 196, y = rr / 14, x = rr % 14;
        atomicOr(&z2p[b * 1568 + oc * 49 + (y >> 1) * 7 + (x >> 1)], zm);
      }
    }
  }
}

// ---------------------------------------------------------------------------
// Stage 3a: dense currents. One wave per (b,t); lane = o. Mask bit is
// wave-uniform -> scalar branch skips inactive f; active f: one coalesced
// 256B row load + add. f strictly ascending (order-exact).
// ---------------------------------------------------------------------------
__global__ __launch_bounds__(64) void k_dense_curB(const unsigned* __restrict__ z2p,
                                                   const float* __restrict__ WdT,
                                                   float* __restrict__ cur) {
  int bt = blockIdx.x;           // b*20 + t
  int b = bt / 20, t = bt % 20;
  int o = threadIdx.x;           // 0..63
  const unsigned* zb = z2p + b * 1568;
  float acc = 0.0f;
  for (int f = 0; f < 1568; ++f) {
    if ((zb[f] >> t) & 1u) acc += WdT[f * 64 + o];
  }
  cur[(b * 64 + o) * 20 + t] = acc;
}

// ---------------------------------------------------------------------------
// Stage 3b: output LIF. One thread per (b,o); writes [B,T,64] f32 spikes.
// ---------------------------------------------------------------------------
__global__ void k_dense_lif(const float* __restrict__ cur, float* __restrict__ out) {
  int idx = blockIdx.x * blockDim.x + threadIdx.x;
  if (idx >= 128 * 64) return;
  int o = idx % 64;
  int b = idx / 64;
  const float* c = cur + (b * 64 + o) * 20;
  float v = 0.0f;
  int   r = 0;
  for (int t = 0; t < 20; ++t) {
    v += c[t];
    bool z = (v > THRF) && (r == 0);
    if (z) { v -= THRF; r = 3; } else if (r > 0) --r;
    out[(b * 20 + t) * 64 + o] = z ? 1.0f : 0.0f;
  }
}

extern "C" void kernel_launch(void* const* d_in, const int* in_sizes, int n_in,
                              void* d_out, int out_size, void* d_ws, size_t ws_size,
                              hipStream_t stream) {
  const float* x  = (const float*)d_in[0];  // [128,1,28,28]
  const float* W1 = (const float*)d_in[1];  // [32,1,3,3]
  const float* W2 = (const float*)d_in[2];  // [32,32,3,3]
  const float* Wd = (const float*)d_in[3];  // [64,1568]
  float* out = (float*)d_out;               // [128,20,64]

  char* ws = (char*)d_ws;
  unsigned* mIn  = (unsigned*)ws;                      // 401408 B (dead after stage1)
  float*    cur  = (float*)ws;                         // 655360 B (reuses mIn region, pre-z1p)
  unsigned* z1p  = (unsigned*)(ws + 655360);           // 3211264 B (zeroed; atomicOr)
  unsigned* z2p  = (unsigned*)(ws + 3866624);          // 802816 B (zeroed; atomicOr)
  unsigned* zbuf = (unsigned*)(ws + 4669440);          // 128 B zeros
  float*    w1T  = (float*)(ws + 4669568);             // 1152 B
  float*    w2T  = (float*)(ws + 4670720);             // 36864 B
  float*    WdT  = (float*)(ws + 4707584);             // 401408 B

  k_encode_mask<<<dim3(392), dim3(256), 0, stream>>>(x, mIn, 128 * 784);
  k_wt<<<dim3(392), dim3(256), 0, stream>>>(W1, W2, Wd, w1T, w2T, WdT);
  hipMemsetAsync(ws + 655360, 0, 3211264 + 802816 + 128, stream);  // z1p+z2p+zbuf
  k_stage1M<<<dim3(25088), dim3(128), 0, stream>>>(mIn, w1T, z1p);
  k_stage2C<<<dim3(4182), dim3(128), 0, stream>>>(z1p, w2T, zbuf, z2p);
  k_dense_curB<<<dim3(2560), dim3(64), 0, stream>>>(z2p, WdT, cur);
  k_dense_lif<<<dim3(32), dim3(256), 0, stream>>>(cur, out);
}

// Round 7
// 370.192 us; speedup vs baseline: 2.3642x; 1.0635x over previous
//
#include <hip/hip_runtime.h>

#define THRF 0.05f

// ---------------------------------------------------------------------------
// Stage 0: latency encode -> one-hot spike mask per pixel (bit t set, or 0)
// ---------------------------------------------------------------------------
__global__ void k_encode_mask(const float* __restrict__ x, unsigned* __restrict__ m, int n) {
  int i = blockIdx.x * blockDim.x + threadIdx.x;
  if (i >= n) return;
  float xv = x[i];
  float st = fminf(19.0f * (1.0f - xv), 19.0f * 0.95f);
  int t = (int)rintf(st);
  t = t < 0 ? 0 : (t > 19 ? 19 : t);
  m[i] = (xv >= THRF) ? (1u << t) : 0u;
}

// ---------------------------------------------------------------------------
// Weight transposes:
//  w1T[k*32+oc]          = W1[oc*9+k]
//  w2T[kk*1024+ic*32+oc] = W2[oc*288+ic*9+kk]
//  WdT[f*64+o]           = Wd[o*1568+f]
// ---------------------------------------------------------------------------
__global__ void k_wt(const float* __restrict__ W1, const float* __restrict__ W2,
                     const float* __restrict__ Wd, float* __restrict__ w1T,
                     float* __restrict__ w2T, float* __restrict__ WdT) {
  int i = blockIdx.x * blockDim.x + threadIdx.x;
  if (i < 288) { int oc = i / 9, k = i % 9; w1T[k * 32 + oc] = W1[i]; }
  if (i < 9216) {
    int oc = i / 288, k = i % 288, ic = k / 9, kk = k % 9;
    w2T[kk * 1024 + ic * 32 + oc] = W2[i];
  }
  if (i < 100352) { int o = i / 1568, f = i % 1568; WdT[f * 64 + o] = Wd[i]; }
}

// ---------------------------------------------------------------------------
// Stage 1: conv1(3x3 SAME, 1->32) + LIF + maxpool, lane-parallel over t.
// (unchanged from passing round-6 kernel)
// ---------------------------------------------------------------------------
__global__ __launch_bounds__(128) void k_stage1M(const unsigned* __restrict__ mIn,
                                                 const float* __restrict__ w1T,
                                                 unsigned* __restrict__ z1p) {
  __shared__ float xp[2][20 * 66];
  int lane = threadIdx.x & 63;
  int wid  = threadIdx.x >> 6;
  int gw   = blockIdx.x * 2 + wid;     // wave index (uniform)
  int pA = 2 * gw, pB = 2 * gw + 1;    // pre-pool pixel = b*784 + y*28 + x
  int bA = pA / 784, rA = pA % 784, yA = rA / 28, xA = rA % 28;
  int bB = pB / 784, rB = pB % 784, yB = rB / 28, xB = rB % 28;
  int tl = lane & 31, hiB = lane >> 5;

  unsigned mA[9], mB[9];
  for (int ky = 0; ky < 3; ++ky) {
    for (int kx = 0; kx < 3; ++kx) {
      int k = ky * 3 + kx;
      int ya = yA - 1 + ky, xa = xA - 1 + kx;
      int yb = yB - 1 + ky, xb = xB - 1 + kx;
      mA[k] = (ya >= 0 && ya < 28 && xa >= 0 && xa < 28) ? mIn[bA * 784 + ya * 28 + xa] : 0u;
      mB[k] = (yb >= 0 && yb < 28 && xb >= 0 && xb < 28) ? mIn[bB * 784 + yb * 28 + xb] : 0u;
    }
  }

  float acc[32];
#pragma unroll
  for (int o = 0; o < 32; ++o) acc[o] = 0.0f;

  for (int k = 0; k < 9; ++k) {
    unsigned long long m64 = ((unsigned long long)mB[k] << 32) | (unsigned long long)mA[k];
    float bitf = (float)((m64 >> lane) & 1ull);
    const float* wrow = w1T + k * 32;
#pragma unroll
    for (int oc = 0; oc < 32; ++oc)
      acc[oc] = fmaf(wrow[oc], bitf, acc[oc]);
  }

  if (tl < 20) {
#pragma unroll
    for (int oc = 0; oc < 32; ++oc)
      xp[wid][tl * 66 + hiB * 32 + oc] = acc[oc];
  }
  __syncthreads();

  float v = 0.0f;
  int   r = 0;
  unsigned zm = 0u;
#pragma unroll
  for (int t = 0; t < 20; ++t) {
    float c = xp[wid][t * 66 + lane];
    v += c;
    bool z = (v > THRF) && (r == 0);
    if (z) { v -= THRF; r = 3; } else if (r > 0) --r;
    if (z) zm |= 1u << t;
  }
  int p = hiB ? pB : pA;
  int b = p / 784, rr = p % 784, y = rr / 28, x = rr % 28;
  atomicOr(&z1p[((b * 14 + (y >> 1)) * 14 + (x >> 1)) * 32 + tl], zm);
}

// ---------------------------------------------------------------------------
// Stage 2: conv2(3x3 SAME, 32->32) + LIF + maxpool, 3 pixels per wave.
// (unchanged from passing round-6 kernel)
// ---------------------------------------------------------------------------
__global__ __launch_bounds__(128) void k_stage2C(const unsigned* __restrict__ z1p,
                                                 const float* __restrict__ wT2,
                                                 const unsigned* __restrict__ zbuf,
                                                 unsigned* __restrict__ z2p) {
  __shared__ float xp[2][20 * 97];
  int lane = threadIdx.x & 63;
  int wid  = threadIdx.x >> 6;
  int gw   = blockIdx.x * 2 + wid;       // wave index (uniform)
  int q0 = 3 * gw, q1 = q0 + 1, q2 = q0 + 2;   // pixels: b*196 + y*14 + x
  bool v0 = q0 < 25088, v1 = q1 < 25088, v2 = q2 < 25088;
  int b0 = q0 / 196, r0 = q0 % 196, y0 = r0 / 14, x0 = r0 % 14;
  int b1 = q1 / 196, r1 = q1 % 196, y1 = r1 / 14, x1 = r1 % 14;
  int b2 = q2 / 196, r2 = q2 % 196, y2 = r2 / 14, x2 = r2 % 14;

  float acc[32];
#pragma unroll
  for (int o = 0; o < 32; ++o) acc[o] = 0.0f;

  for (int ky = 0; ky < 3; ++ky) {
    int y0k = y0 - 1 + ky, y1k = y1 - 1 + ky, y2k = y2 - 1 + ky;
    for (int kx = 0; kx < 3; ++kx) {
      int x0k = x0 - 1 + kx, x1k = x1 - 1 + kx, x2k = x2 - 1 + kx;
      bool ok0 = v0 && y0k >= 0 && y0k < 14 && x0k >= 0 && x0k < 14;
      bool ok1 = v1 && y1k >= 0 && y1k < 14 && x1k >= 0 && x1k < 14;
      bool ok2 = v2 && y2k >= 0 && y2k < 14 && x2k >= 0 && x2k < 14;
      const unsigned* c0 = ok0 ? (z1p + ((b0 * 14 + y0k) * 14 + x0k) * 32) : zbuf;
      const unsigned* c1 = ok1 ? (z1p + ((b1 * 14 + y1k) * 14 + x1k) * 32) : zbuf;
      const unsigned* c2 = ok2 ? (z1p + ((b2 * 14 + y2k) * 14 + x2k) * 32) : zbuf;
      const float* wc = wT2 + (ky * 3 + kx) * 1024;
#pragma unroll
      for (int ic = 0; ic < 32; ++ic) {
        unsigned long long B = (unsigned long long)c0[ic] |
                               ((unsigned long long)c1[ic] << 20) |
                               ((unsigned long long)c2[ic] << 40);
        float bitf = (float)((B >> lane) & 1ull);   // lane = p*20 + t
        const float* wrow = wc + ic * 32;
#pragma unroll
        for (int oc = 0; oc < 32; ++oc)
          acc[oc] = fmaf(wrow[oc], bitf, acc[oc]);
      }
    }
  }

  int pl = lane / 20;
  int tl = lane - pl * 20;
  if (pl < 3) {
#pragma unroll
    for (int oc = 0; oc < 32; ++oc)
      xp[wid][tl * 97 + pl * 32 + oc] = acc[oc];
  }
  __syncthreads();

  for (int pass = 0; pass < 2; ++pass) {
    int n = lane + 64 * pass;
    if (n < 96) {
      int pp = n >> 5;
      int oc = n & 31;
      int q  = q0 + pp;
      if (q < 25088) {
        float v = 0.0f;
        int   r = 0;
        unsigned zm = 0u;
#pragma unroll
        for (int t = 0; t < 20; ++t) {
          float c = xp[wid][t * 97 + n];
          v += c;
          bool z = (v > THRF) && (r == 0);
          if (z) { v -= THRF; r = 3; } else if (r > 0) --r;
          if (z) zm |= 1u << t;
        }
        int b = q / 196, rr = q % 196, y = rr / 14, x = rr % 14;
        atomicOr(&z2p[b * 1568 + oc * 49 + (y >> 1) * 7 + (x >> 1)], zm);
      }
    }
  }
}

// ---------------------------------------------------------------------------
// Stage 3a REWRITE: dense currents, 3-way lane-packed and BRANCHLESS.
// Wave = (b, o-triple og); lane = p*20 + t, o = og*3+p (lanes with p==3 or
// o>=64 idle/discarded). Per f: uniform scalar mask m = zb[f]; B replicates
// m into three 20-bit fields (SALU multiply); per-lane bit extract + ONE
// unconditional fmaf with a coalesced per-lane weight load. Loads are
// independent across f -> compiler unrolls & pipelines (fixes round-6's
// serialized scalar-branch chain, VALUBusy 1.7%).
// f strictly ascending per (b,o,t): reduction order unchanged; bit=0 terms
// add +0.0 (exact no-op), same exactness argument as stages 1/2.
// ---------------------------------------------------------------------------
__global__ __launch_bounds__(128) void k_dense_curC(const unsigned* __restrict__ z2p,
                                                    const float* __restrict__ WdT,
                                                    float* __restrict__ cur) {
  int lane = threadIdx.x & 63;
  int wid  = threadIdx.x >> 6;
  int gw   = blockIdx.x * 2 + wid;     // 0..2815 = b*22 + og
  if (gw >= 128 * 22) return;
  int b  = gw / 22, og = gw % 22;
  int p  = lane / 20;                  // 0..3 (p==3 -> idle)
  int t  = lane - p * 20;
  int o  = og * 3 + p;
  bool live = (p < 3) && (o < 64);
  int osafe = live ? o : 63;
  const unsigned* zb = z2p + b * 1568;
  float acc = 0.0f;
  for (int f = 0; f < 1568; ++f) {
    unsigned m = zb[f];                                        // wave-uniform
    unsigned long long B = (unsigned long long)m * 0x0000010000100001ull;
    float w    = WdT[f * 64 + osafe];
    float bitf = (float)((B >> lane) & 1ull);                  // bit t of field p
    acc = fmaf(w, bitf, acc);
  }
  if (live) cur[(b * 64 + o) * 20 + t] = acc;
}

// ---------------------------------------------------------------------------
// Stage 3b: output LIF (unchanged). One thread per (b,o) -> [B,T,64] f32.
// ---------------------------------------------------------------------------
__global__ void k_dense_lif(const float* __restrict__ cur, float* __restrict__ out) {
  int idx = blockIdx.x * blockDim.x + threadIdx.x;
  if (idx >= 128 * 64) return;
  int o = idx % 64;
  int b = idx / 64;
  const float* c = cur + (b * 64 + o) * 20;
  float v = 0.0f;
  int   r = 0;
  for (int t = 0; t < 20; ++t) {
    v += c[t];
    bool z = (v > THRF) && (r == 0);
    if (z) { v -= THRF; r = 3; } else if (r > 0) --r;
    out[(b * 20 + t) * 64 + o] = z ? 1.0f : 0.0f;
  }
}

extern "C" void kernel_launch(void* const* d_in, const int* in_sizes, int n_in,
                              void* d_out, int out_size, void* d_ws, size_t ws_size,
                              hipStream_t stream) {
  const float* x  = (const float*)d_in[0];  // [128,1,28,28]
  const float* W1 = (const float*)d_in[1];  // [32,1,3,3]
  const float* W2 = (const float*)d_in[2];  // [32,32,3,3]
  const float* Wd = (const float*)d_in[3];  // [64,1568]
  float* out = (float*)d_out;               // [128,20,64]

  char* ws = (char*)d_ws;
  unsigned* mIn  = (unsigned*)ws;                      // 401408 B (dead after stage1)
  float*    cur  = (float*)ws;                         // 655360 B (reuses mIn region)
  unsigned* z1p  = (unsigned*)(ws + 655360);           // 3211264 B (zeroed; atomicOr)
  unsigned* z2p  = (unsigned*)(ws + 3866624);          // 802816 B (zeroed; atomicOr)
  unsigned* zbuf = (unsigned*)(ws + 4669440);          // 128 B zeros
  float*    w1T  = (float*)(ws + 4669568);             // 1152 B
  float*    w2T  = (float*)(ws + 4670720);             // 36864 B
  float*    WdT  = (float*)(ws + 4707584);             // 401408 B

  k_encode_mask<<<dim3(392), dim3(256), 0, stream>>>(x, mIn, 128 * 784);
  k_wt<<<dim3(392), dim3(256), 0, stream>>>(W1, W2, Wd, w1T, w2T, WdT);
  hipMemsetAsync(ws + 655360, 0, 3211264 + 802816 + 128, stream);  // z1p+z2p+zbuf
  k_stage1M<<<dim3(25088), dim3(128), 0, stream>>>(mIn, w1T, z1p);
  k_stage2C<<<dim3(4182), dim3(128), 0, stream>>>(z1p, w2T, zbuf, z2p);
  k_dense_curC<<<dim3(1408), dim3(128), 0, stream>>>(z2p, WdT, cur);
  k_dense_lif<<<dim3(32), dim3(256), 0, stream>>>(cur, out);
}